// Round 5
// baseline (791.462 us; speedup 1.0000x reference)
//
#include <hip/hip_runtime.h>
#include <hip/hip_fp16.h>
#include <math.h>

#define NU 100000
#define NB 50000
#define NI 100000
#define D 64
#define NLAYER 3
#define NNZ 2000000
#define BATCH 8192
#define LEAKY 0.2f
#define N_UB (NU + NB)   // 150000
#define N_IU (NI + NU)   // 200000

#define VSCALE 16383.f   // 14-bit fixed-point for vals in [0,1)

// ---- windowed CSR build params ----
#define WBITS 14
#define WSZ 16384                      // node window
#define NWC 13                         // ceil(200000/16384)
#define NWR 10                         // ceil(150000/16384)
#define NWIN (NWC + NWR)               // 23
#define CAPC 184320                    // >= binom mean 163840 + 50 sigma
#define CAPR 245760                    // >= binom mean 218453 + 60 sigma
#define EPB 8192                       // edges per bucket block
#define NBLK_B ((NNZ + EPB - 1) / EPB) // 245
#define CONCAT_BLKS 512
#define PADI(i) ((i) + ((i) >> 4))     // LDS bank-conflict pad (17 per 16)
#define LTOT 17408                     // > PADI(16383)=17406

typedef unsigned long long u64;

// ---------------------------------------------------------------------------
// bucket pass: partition edges into node-windows for both sides.
// record: payload32 = q<<18 | partner ; rec = payload<<14 | node_local
// per-block LDS counts -> 23 global atomics per block (not 4M).
// ---------------------------------------------------------------------------
__global__ __launch_bounds__(1024) void bucket_kernel(
    const int* __restrict__ rows, const int* __restrict__ cols,
    const float* __restrict__ vals, int* __restrict__ gcurC,
    int* __restrict__ gcurR, u64* __restrict__ bufC, u64* __restrict__ bufR) {
  __shared__ int cntw[NWIN];
  __shared__ int basew[NWIN];
  int t = threadIdx.x;
  if (t < NWIN) cntw[t] = 0;
  __syncthreads();
  int e0 = blockIdx.x * EPB;
  int e1 = e0 + EPB;
  if (e1 > NNZ) e1 = NNZ;
  // pass 1: count per window
  for (int e = e0 + t; e < e1; e += 1024) {
    int c = cols[e];
    int r = rows[e];
    atomicAdd(&cntw[c >> WBITS], 1);
    atomicAdd(&cntw[NWC + (r >> WBITS)], 1);
  }
  __syncthreads();
  if (t < NWC)
    basew[t] = atomicAdd(&gcurC[t], cntw[t]);
  else if (t < NWIN)
    basew[t] = atomicAdd(&gcurR[t - NWC], cntw[t]);
  __syncthreads();
  if (t < NWIN) cntw[t] = 0;  // reuse as local cursors
  __syncthreads();
  // pass 2: write records
  for (int e = e0 + t; e < e1; e += 1024) {
    int c = cols[e];
    int r = rows[e];
    unsigned q = __float2uint_rn(vals[e] * VSCALE);
    int wc = c >> WBITS;
    int wr = r >> WBITS;
    int oc = atomicAdd(&cntw[wc], 1);
    u64 recC = ((u64)((q << 18) | (unsigned)r) << WBITS) |
               (unsigned)(c & (WSZ - 1));
    bufC[(size_t)wc * CAPC + basew[wc] + oc] = recC;
    int orr = atomicAdd(&cntw[NWC + wr], 1);
    u64 recR = ((u64)((q << 18) | (unsigned)c) << WBITS) |
               (unsigned)(r & (WSZ - 1));
    bufR[(size_t)wr * CAPR + basew[NWC + wr] + orr] = recR;
  }
}

// ---------------------------------------------------------------------------
// fused dispatch:
//   blocks [0, NWIN): per-window LDS counting sort -> ptr slice + ec/er
//   blocks [NWIN, NWIN+CONCAT_BLKS): concat emb->x(fp16) + l2 reduction
// ---------------------------------------------------------------------------
__global__ __launch_bounds__(1024) void csr_concat_kernel(
    const u64* __restrict__ bufC, const u64* __restrict__ bufR,
    const int* __restrict__ gcurC, const int* __restrict__ gcurR,
    unsigned* __restrict__ ec, unsigned* __restrict__ er,
    int* __restrict__ ptrc, int* __restrict__ ptrr,
    const float* __restrict__ emb_u, const float* __restrict__ emb_b,
    __half* __restrict__ x, float* __restrict__ out) {
  __shared__ int lcnt[LTOT];
  __shared__ int part[1024];
  __shared__ float fsum[16];
  int blk = blockIdx.x;
  int t = threadIdx.x;

  if (blk >= NWIN) {
    // ---------------- concat + l2 path ----------------
    const int total4 = (N_UB * D) / 4;
    const int nu4 = (NU * D) / 4;
    float sq = 0.f;
    for (int i = (blk - NWIN) * 1024 + t; i < total4; i += CONCAT_BLKS * 1024) {
      float4 v = (i < nu4) ? ((const float4*)emb_u)[i]
                           : ((const float4*)emb_b)[i - nu4];
      sq += v.x * v.x + v.y * v.y + v.z * v.z + v.w * v.w;
      union { __half2 h[2]; int2 p; } u;
      u.h[0] = __floats2half2_rn(v.x, v.y);
      u.h[1] = __floats2half2_rn(v.z, v.w);
      ((int2*)x)[i] = u.p;
    }
    for (int off = 32; off; off >>= 1) sq += __shfl_down(sq, off);
    if ((t & 63) == 0) fsum[t >> 6] = sq;
    __syncthreads();
    if (t == 0) {
      float s = 0.f;
      for (int k = 0; k < 16; ++k) s += fsum[k];
      atomicAdd(&out[1], s * (0.5f / (float)NU));
    }
    return;
  }

  // ---------------- windowed counting-sort path ----------------
  bool cside = blk < NWC;
  int win = cside ? blk : blk - NWC;
  const u64* buf = cside ? bufC + (size_t)win * CAPC : bufR + (size_t)win * CAPR;
  const int* gsz = cside ? gcurC : gcurR;
  int nwin = cside ? NWC : NWR;
  int nnode = cside ? N_IU : N_UB;
  unsigned* eo = cside ? ec : er;
  int* ptr = cside ? ptrc : ptrr;
  int cnt = gsz[win];
  int winbase = 0;
  for (int w = 0; w < win; ++w) winbase += gsz[w];

  for (int i = t; i < LTOT; i += 1024) lcnt[i] = 0;
  __syncthreads();
  // pass 1: histogram over window-local node ids
  for (int i = t; i < cnt; i += 1024) {
    int loc = (int)(buf[i] & (WSZ - 1));
    atomicAdd(&lcnt[PADI(loc)], 1);
  }
  __syncthreads();
  // exclusive scan of 16384 counters: serial-16 per thread + block scan
  int base16 = t * 16;
  int s = 0;
  for (int k = 0; k < 16; ++k) {
    int idx = PADI(base16 + k);
    int v = lcnt[idx];
    lcnt[idx] = s;
    s += v;
  }
  part[t] = s;
  __syncthreads();
  for (int off = 1; off < 1024; off <<= 1) {
    int v = (t >= off) ? part[t - off] : 0;
    __syncthreads();
    part[t] += v;
    __syncthreads();
  }
  int excl = part[t] - s;
  for (int k = 0; k < 16; ++k) lcnt[PADI(base16 + k)] += excl;
  __syncthreads();
  // write global ptr slice
  int gnode0 = win * WSZ;
  for (int j = t; j < WSZ; j += 1024) {
    int g = gnode0 + j;
    if (g < nnode) ptr[g] = winbase + lcnt[PADI(j)];
  }
  if (t == 0 && win == nwin - 1) ptr[nnode] = NNZ;
  __syncthreads();
  // pass 2: scatter payloads (window's output region is L2-resident)
  for (int i = t; i < cnt; i += 1024) {
    u64 rec = buf[i];
    int loc = (int)(rec & (WSZ - 1));
    int pos = winbase + atomicAdd(&lcnt[PADI(loc)], 1);
    eo[pos] = (unsigned)(rec >> WBITS);
  }
}

// ---------------------------------------------------------------------------
// pass 1 (CSR by col): y[c] = leaky(filt[c]) * sum val*x[src]
// half-wave per row, half2 per lane; unroll 4; NT loads on edge stream.
// ---------------------------------------------------------------------------
__global__ __launch_bounds__(256) void spmm_col_kernel(
    const int* __restrict__ ptrc, const unsigned* __restrict__ ec,
    const __half* __restrict__ x, const float* __restrict__ filt,
    __half* __restrict__ y) {
  int w = blockIdx.x * 4 + (threadIdx.x >> 6);
  int c = w * 2 + ((threadIdx.x >> 5) & 1);
  if (c >= N_IU) return;
  int sub = threadIdx.x & 31;
  int e = ptrc[c], e2 = ptrc[c + 1];
  float ax = 0.f, ay = 0.f;
  for (; e + 4 <= e2; e += 4) {
    unsigned p0 = __builtin_nontemporal_load(&ec[e]);
    unsigned p1 = __builtin_nontemporal_load(&ec[e + 1]);
    unsigned p2 = __builtin_nontemporal_load(&ec[e + 2]);
    unsigned p3 = __builtin_nontemporal_load(&ec[e + 3]);
    float2 x0 = __half22float2(
        *(const __half2*)&x[(size_t)(p0 & 0x3FFFFu) * D + 2 * sub]);
    float2 x1 = __half22float2(
        *(const __half2*)&x[(size_t)(p1 & 0x3FFFFu) * D + 2 * sub]);
    float2 x2 = __half22float2(
        *(const __half2*)&x[(size_t)(p2 & 0x3FFFFu) * D + 2 * sub]);
    float2 x3 = __half22float2(
        *(const __half2*)&x[(size_t)(p3 & 0x3FFFFu) * D + 2 * sub]);
    float v0 = (float)(p0 >> 18), v1 = (float)(p1 >> 18);
    float v2 = (float)(p2 >> 18), v3 = (float)(p3 >> 18);
    ax += v0 * x0.x + v1 * x1.x + v2 * x2.x + v3 * x3.x;
    ay += v0 * x0.y + v1 * x1.y + v2 * x2.y + v3 * x3.y;
  }
  for (; e < e2; ++e) {
    unsigned p = __builtin_nontemporal_load(&ec[e]);
    float2 xv = __half22float2(
        *(const __half2*)&x[(size_t)(p & 0x3FFFFu) * D + 2 * sub]);
    float v = (float)(p >> 18);
    ax += v * xv.x;
    ay += v * xv.y;
  }
  float fw = filt[c];
  float f = (fw > 0.f ? fw : LEAKY * fw) * (1.f / VSCALE);
  *(__half2*)&y[(size_t)c * D + 2 * sub] = __floats2half2_rn(ax * f, ay * f);
}

// ---------------------------------------------------------------------------
// pass 2 (CSR by row): x[r] = sum val*y[src]
// ---------------------------------------------------------------------------
__global__ __launch_bounds__(256) void spmm_row_kernel(
    const int* __restrict__ ptrr, const unsigned* __restrict__ er,
    const __half* __restrict__ y, __half* __restrict__ x) {
  int w = blockIdx.x * 4 + (threadIdx.x >> 6);
  int r = w * 2 + ((threadIdx.x >> 5) & 1);
  if (r >= N_UB) return;
  int sub = threadIdx.x & 31;
  int e = ptrr[r], e2 = ptrr[r + 1];
  float ax = 0.f, ay = 0.f;
  for (; e + 4 <= e2; e += 4) {
    unsigned p0 = __builtin_nontemporal_load(&er[e]);
    unsigned p1 = __builtin_nontemporal_load(&er[e + 1]);
    unsigned p2 = __builtin_nontemporal_load(&er[e + 2]);
    unsigned p3 = __builtin_nontemporal_load(&er[e + 3]);
    float2 y0 = __half22float2(
        *(const __half2*)&y[(size_t)(p0 & 0x3FFFFu) * D + 2 * sub]);
    float2 y1 = __half22float2(
        *(const __half2*)&y[(size_t)(p1 & 0x3FFFFu) * D + 2 * sub]);
    float2 y2 = __half22float2(
        *(const __half2*)&y[(size_t)(p2 & 0x3FFFFu) * D + 2 * sub]);
    float2 y3 = __half22float2(
        *(const __half2*)&y[(size_t)(p3 & 0x3FFFFu) * D + 2 * sub]);
    float v0 = (float)(p0 >> 18), v1 = (float)(p1 >> 18);
    float v2 = (float)(p2 >> 18), v3 = (float)(p3 >> 18);
    ax += v0 * y0.x + v1 * y1.x + v2 * y2.x + v3 * y3.x;
    ay += v0 * y0.y + v1 * y1.y + v2 * y2.y + v3 * y3.y;
  }
  for (; e < e2; ++e) {
    unsigned p = __builtin_nontemporal_load(&er[e]);
    float2 yv = __half22float2(
        *(const __half2*)&y[(size_t)(p & 0x3FFFFu) * D + 2 * sub]);
    float v = (float)(p >> 18);
    ax += v * yv.x;
    ay += v * yv.y;
  }
  *(__half2*)&x[(size_t)r * D + 2 * sub] =
      __floats2half2_rn(ax * (1.f / VSCALE), ay * (1.f / VSCALE));
}

// ---------------------------------------------------------------------------
// last layer pass 2 ONLY at gathered rows, accumulated into uacc/bacc (fp32)
// ---------------------------------------------------------------------------
__global__ __launch_bounds__(256) void spmm_gather_last_kernel(
    const int* __restrict__ ptrr, const unsigned* __restrict__ er,
    const __half* __restrict__ y, const int* __restrict__ u_idx,
    const int* __restrict__ b_idx, float* __restrict__ uacc,
    float* __restrict__ bacc) {
  int w = blockIdx.x * 4 + (threadIdx.x >> 6);
  int i = w * 2 + ((threadIdx.x >> 5) & 1);
  if (i >= 3 * BATCH) return;
  int sub = threadIdx.x & 31;
  int row;
  float* dst;
  if (i < BATCH) {
    row = u_idx[i];
    dst = &uacc[(size_t)i * D];
  } else {
    int j = i - BATCH;
    row = NU + b_idx[j];
    dst = &bacc[(size_t)j * D];
  }
  int e = ptrr[row], e2 = ptrr[row + 1];
  float ax = 0.f, ay = 0.f;
  for (; e + 2 <= e2; e += 2) {
    unsigned p0 = er[e], p1 = er[e + 1];
    float2 y0 = __half22float2(
        *(const __half2*)&y[(size_t)(p0 & 0x3FFFFu) * D + 2 * sub]);
    float2 y1 = __half22float2(
        *(const __half2*)&y[(size_t)(p1 & 0x3FFFFu) * D + 2 * sub]);
    float v0 = (float)(p0 >> 18), v1 = (float)(p1 >> 18);
    ax += v0 * y0.x + v1 * y1.x;
    ay += v0 * y0.y + v1 * y1.y;
  }
  if (e < e2) {
    unsigned p = er[e];
    float2 yv = __half22float2(
        *(const __half2*)&y[(size_t)(p & 0x3FFFFu) * D + 2 * sub]);
    float v = (float)(p >> 18);
    ax += v * yv.x;
    ay += v * yv.y;
  }
  float2* dp = (float2*)&dst[2 * sub];
  float2 d = *dp;
  d.x += ax * (1.f / VSCALE);
  d.y += ay * (1.f / VSCALE);
  *dp = d;
}

// ---------------------------------------------------------------------------
// gather-accumulate (x0 + intermediate layers)
// ---------------------------------------------------------------------------
__global__ __launch_bounds__(256) void gather_acc_kernel(
    const __half* __restrict__ x, const int* __restrict__ u_idx,
    const int* __restrict__ b_idx, float* __restrict__ uacc,
    float* __restrict__ bacc) {
  int w = blockIdx.x * 4 + (threadIdx.x >> 6);
  int i = w * 2 + ((threadIdx.x >> 5) & 1);
  if (i >= 3 * BATCH) return;
  int sub = threadIdx.x & 31;
  int src;
  float* dst;
  if (i < BATCH) {
    src = u_idx[i];
    dst = &uacc[(size_t)i * D];
  } else {
    int j = i - BATCH;
    src = NU + b_idx[j];
    dst = &bacc[(size_t)j * D];
  }
  float2 xf =
      __half22float2(*(const __half2*)&x[(size_t)src * D + 2 * sub]);
  float2* dp = (float2*)&dst[2 * sub];
  float2 d = *dp;
  d.x += xf.x;
  d.y += xf.y;
  *dp = d;
}

// ---------------------------------------------------------------------------
// loss
// ---------------------------------------------------------------------------
__global__ __launch_bounds__(256) void loss_kernel(
    const float* __restrict__ uacc, const float* __restrict__ bacc,
    float* __restrict__ out) {
  int w = blockIdx.x * 4 + (threadIdx.x >> 6);
  int i = w * 2 + ((threadIdx.x >> 5) & 1);
  if (i >= BATCH) return;
  int sub = threadIdx.x & 31;
  float2 u = *(const float2*)&uacc[(size_t)i * D + 2 * sub];
  float2 b0 = *(const float2*)&bacc[(size_t)(2 * i) * D + 2 * sub];
  float2 b1 = *(const float2*)&bacc[(size_t)(2 * i + 1) * D + 2 * sub];
  float t = (u.x * (b1.x - b0.x) + u.y * (b1.y - b0.y)) * (1.f / 16.f);
  for (int off = 16; off; off >>= 1) t += __shfl_down(t, off, 32);
  if (sub == 0) {
    float z = t;
    float sp = z > 0.f ? z + log1pf(expf(-z)) : log1pf(expf(z));
    atomicAdd(&out[0], sp * (1.f / (float)BATCH));
  }
}

extern "C" void kernel_launch(void* const* d_in, const int* in_sizes, int n_in,
                              void* d_out, int out_size, void* d_ws,
                              size_t ws_size, hipStream_t stream) {
  const float* emb_u = (const float*)d_in[0];
  const float* emb_b = (const float*)d_in[1];
  const float* filter_w = (const float*)d_in[2];
  const float* vals = (const float*)d_in[3];
  const int* rows = (const int*)d_in[4];
  const int* cols = (const int*)d_in[5];
  const int* u_idx = (const int*)d_in[6];
  const int* b_idx = (const int*)d_in[7];
  float* out = (float*)d_out;

  // workspace layout (u64 buffers first for 8B alignment)
  u64* bufC = (u64*)d_ws;                              // 13*CAPC
  u64* bufR = bufC + (size_t)NWC * CAPC;               // 10*CAPR
  __half* xA = (__half*)(bufR + (size_t)NWR * CAPR);   // N_UB*D halves
  __half* yH = xA + (size_t)N_UB * D;                  // N_IU*D halves
  float* uacc = (float*)(yH + (size_t)N_IU * D);       // BATCH*D
  float* bacc = uacc + (size_t)BATCH * D;              // 2*BATCH*D
  unsigned* ec = (unsigned*)(bacc + (size_t)2 * BATCH * D);  // NNZ
  unsigned* er = ec + NNZ;                             // NNZ
  int* ptrc = (int*)(er + NNZ);                        // N_IU+1
  int* ptrr = ptrc + (N_IU + 1);                       // N_UB+1
  int* gcurC = ptrr + (N_UB + 1);                      // NWC
  int* gcurR = gcurC + NWC;                            // NWR

  hipMemsetAsync(out, 0, 2 * sizeof(float), stream);
  hipMemsetAsync(uacc, 0, (size_t)3 * BATCH * D * sizeof(float), stream);
  hipMemsetAsync(gcurC, 0, NWIN * sizeof(int), stream);

  // bucket edges by node-window (both sides)
  bucket_kernel<<<NBLK_B, 1024, 0, stream>>>(rows, cols, vals, gcurC, gcurR,
                                             bufC, bufR);
  // per-window LDS counting sort (-> ptr + ec/er), fused with concat+l2
  csr_concat_kernel<<<NWIN + CONCAT_BLKS, 1024, 0, stream>>>(
      bufC, bufR, gcurC, gcurR, ec, er, ptrc, ptrr, emb_u, emb_b, xA, out);
  // x0 contribution to gathered rows
  gather_acc_kernel<<<(3 * BATCH + 7) / 8, 256, 0, stream>>>(xA, u_idx, b_idx,
                                                             uacc, bacc);

  // ---- 3 layers ----
  for (int l = 0; l < NLAYER; ++l) {
    spmm_col_kernel<<<(N_IU + 7) / 8, 256, 0, stream>>>(
        ptrc, ec, xA, filter_w + (size_t)l * N_IU, yH);
    if (l < NLAYER - 1) {
      spmm_row_kernel<<<(N_UB + 7) / 8, 256, 0, stream>>>(ptrr, er, yH, xA);
      gather_acc_kernel<<<(3 * BATCH + 7) / 8, 256, 0, stream>>>(
          xA, u_idx, b_idx, uacc, bacc);
    } else {
      spmm_gather_last_kernel<<<(3 * BATCH + 7) / 8, 256, 0, stream>>>(
          ptrr, er, yH, u_idx, b_idx, uacc, bacc);
    }
  }

  loss_kernel<<<(BATCH + 7) / 8, 256, 0, stream>>>(uacc, bacc, out);
}

// Round 6
// 542.419 us; speedup vs baseline: 1.4591x; 1.4591x over previous
//
#include <hip/hip_runtime.h>
#include <hip/hip_fp16.h>
#include <math.h>

#define NU 100000
#define NB 50000
#define NI 100000
#define D 64
#define NLAYER 3
#define NNZ 2000000
#define BATCH 8192
#define LEAKY 0.2f
#define N_UB (NU + NB)   // 150000
#define N_IU (NI + NU)   // 200000

#define VSCALE 16383.f   // 14-bit fixed-point for vals in [0,1)

// ---- windowed CSR build params ----
#define WBITS 11
#define WSZ 2048                        // node window (small -> many blocks)
#define NWC ((N_IU + WSZ - 1) / WSZ)    // 98
#define NWR ((N_UB + WSZ - 1) / WSZ)    // 74
#define NWIN (NWC + NWR)                // 172
#define CAPC 21504                      // mean 20480 + 7.2 sigma
#define CAPR 28672                      // mean 27307 + 8.3 sigma
#define EPB 8192                        // edges per bucket block
#define NBLK_B ((NNZ + EPB - 1) / EPB)  // 245
#define CONCAT_BLKS 512

typedef unsigned long long u64;

// ---------------------------------------------------------------------------
// bucket pass: partition edges into 2048-node windows for both sides.
// record: payload32 = q<<18 | partner ; rec = payload<<11 | node_local
// per-block LDS counts -> NWIN global atomics per block (not 4M).
// ---------------------------------------------------------------------------
__global__ __launch_bounds__(1024) void bucket_kernel(
    const int* __restrict__ rows, const int* __restrict__ cols,
    const float* __restrict__ vals, int* __restrict__ gcurC,
    int* __restrict__ gcurR, u64* __restrict__ bufC, u64* __restrict__ bufR) {
  __shared__ int cntw[NWIN];
  __shared__ int basew[NWIN];
  int t = threadIdx.x;
  if (t < NWIN) cntw[t] = 0;
  __syncthreads();
  int e0 = blockIdx.x * EPB;
  int e1 = e0 + EPB;
  if (e1 > NNZ) e1 = NNZ;
  // pass 1: count per window
  for (int e = e0 + t; e < e1; e += 1024) {
    int c = cols[e];
    int r = rows[e];
    atomicAdd(&cntw[c >> WBITS], 1);
    atomicAdd(&cntw[NWC + (r >> WBITS)], 1);
  }
  __syncthreads();
  if (t < NWC)
    basew[t] = atomicAdd(&gcurC[t], cntw[t]);
  else if (t < NWIN)
    basew[t] = atomicAdd(&gcurR[t - NWC], cntw[t]);
  __syncthreads();
  if (t < NWIN) cntw[t] = 0;  // reuse as local cursors
  __syncthreads();
  // pass 2: write records
  for (int e = e0 + t; e < e1; e += 1024) {
    int c = cols[e];
    int r = rows[e];
    unsigned q = __float2uint_rn(vals[e] * VSCALE);
    int wc = c >> WBITS;
    int wr = r >> WBITS;
    int oc = atomicAdd(&cntw[wc], 1);
    u64 recC = ((u64)((q << 18) | (unsigned)r) << WBITS) |
               (unsigned)(c & (WSZ - 1));
    bufC[(size_t)wc * CAPC + basew[wc] + oc] = recC;
    int orr = atomicAdd(&cntw[NWC + wr], 1);
    u64 recR = ((u64)((q << 18) | (unsigned)c) << WBITS) |
               (unsigned)(r & (WSZ - 1));
    bufR[(size_t)wr * CAPR + basew[NWC + wr] + orr] = recR;
  }
}

// ---------------------------------------------------------------------------
// fused dispatch:
//   blocks [0, NWIN): per-window LDS counting sort -> ptr slice + ec/er
//   blocks [NWIN, NWIN+CONCAT_BLKS): concat emb->x(fp16) + l2 reduction
// ---------------------------------------------------------------------------
__global__ __launch_bounds__(1024) void csr_concat_kernel(
    const u64* __restrict__ bufC, const u64* __restrict__ bufR,
    const int* __restrict__ gcurC, const int* __restrict__ gcurR,
    unsigned* __restrict__ ec, unsigned* __restrict__ er,
    int* __restrict__ ptrc, int* __restrict__ ptrr,
    const float* __restrict__ emb_u, const float* __restrict__ emb_b,
    __half* __restrict__ x, float* __restrict__ out) {
  __shared__ int lcnt[WSZ];
  __shared__ int part[1024];
  __shared__ float fsum[16];
  int blk = blockIdx.x;
  int t = threadIdx.x;

  if (blk >= NWIN) {
    // ---------------- concat + l2 path ----------------
    const int total4 = (N_UB * D) / 4;
    const int nu4 = (NU * D) / 4;
    float sq = 0.f;
    for (int i = (blk - NWIN) * 1024 + t; i < total4; i += CONCAT_BLKS * 1024) {
      float4 v = (i < nu4) ? ((const float4*)emb_u)[i]
                           : ((const float4*)emb_b)[i - nu4];
      sq += v.x * v.x + v.y * v.y + v.z * v.z + v.w * v.w;
      union { __half2 h[2]; int2 p; } u;
      u.h[0] = __floats2half2_rn(v.x, v.y);
      u.h[1] = __floats2half2_rn(v.z, v.w);
      ((int2*)x)[i] = u.p;
    }
    for (int off = 32; off; off >>= 1) sq += __shfl_down(sq, off);
    if ((t & 63) == 0) fsum[t >> 6] = sq;
    __syncthreads();
    if (t == 0) {
      float s = 0.f;
      for (int k = 0; k < 16; ++k) s += fsum[k];
      atomicAdd(&out[1], s * (0.5f / (float)NU));
    }
    return;
  }

  // ---------------- windowed counting-sort path ----------------
  bool cside = blk < NWC;
  int win = cside ? blk : blk - NWC;
  const u64* buf = cside ? bufC + (size_t)win * CAPC : bufR + (size_t)win * CAPR;
  const int* gsz = cside ? gcurC : gcurR;
  int nwin = cside ? NWC : NWR;
  int nnode = cside ? N_IU : N_UB;
  unsigned* eo = cside ? ec : er;
  int* ptr = cside ? ptrc : ptrr;
  int cnt = gsz[win];
  int winbase = 0;
  for (int w = 0; w < win; ++w) winbase += gsz[w];

  lcnt[t] = 0;
  lcnt[t + 1024] = 0;
  __syncthreads();
  // pass 1: histogram over window-local node ids
  for (int i = t; i < cnt; i += 1024)
    atomicAdd(&lcnt[(int)(buf[i] & (WSZ - 1))], 1);
  __syncthreads();
  // exclusive scan of 2048 counters: 2 serial per thread + block scan
  int i0 = 2 * t;
  int a = lcnt[i0], b = lcnt[i0 + 1];
  int s = a + b;
  part[t] = s;
  __syncthreads();
  for (int off = 1; off < 1024; off <<= 1) {
    int v = (t >= off) ? part[t - off] : 0;
    __syncthreads();
    part[t] += v;
    __syncthreads();
  }
  int excl = part[t] - s;
  lcnt[i0] = excl;
  lcnt[i0 + 1] = excl + a;
  __syncthreads();
  // write global ptr slice
  int gnode0 = win * WSZ;
  for (int j = t; j < WSZ; j += 1024) {
    int g = gnode0 + j;
    if (g < nnode) ptr[g] = winbase + lcnt[j];
  }
  if (t == 0 && win == nwin - 1) ptr[nnode] = NNZ;
  __syncthreads();
  // pass 2: scatter payloads (window's ~80KB output region is L2-resident)
  for (int i = t; i < cnt; i += 1024) {
    u64 rec = buf[i];
    int pos = winbase + atomicAdd(&lcnt[(int)(rec & (WSZ - 1))], 1);
    eo[pos] = (unsigned)(rec >> WBITS);
  }
}

// ---------------------------------------------------------------------------
// pass 1 (CSR by col): y[c] = leaky(filt[c]) * sum val*x[src]
// half-wave per row, half2 per lane; unroll 4; NT loads on edge stream.
// ---------------------------------------------------------------------------
__global__ __launch_bounds__(256) void spmm_col_kernel(
    const int* __restrict__ ptrc, const unsigned* __restrict__ ec,
    const __half* __restrict__ x, const float* __restrict__ filt,
    __half* __restrict__ y) {
  int w = blockIdx.x * 4 + (threadIdx.x >> 6);
  int c = w * 2 + ((threadIdx.x >> 5) & 1);
  if (c >= N_IU) return;
  int sub = threadIdx.x & 31;
  int e = ptrc[c], e2 = ptrc[c + 1];
  float ax = 0.f, ay = 0.f;
  for (; e + 4 <= e2; e += 4) {
    unsigned p0 = __builtin_nontemporal_load(&ec[e]);
    unsigned p1 = __builtin_nontemporal_load(&ec[e + 1]);
    unsigned p2 = __builtin_nontemporal_load(&ec[e + 2]);
    unsigned p3 = __builtin_nontemporal_load(&ec[e + 3]);
    float2 x0 = __half22float2(
        *(const __half2*)&x[(size_t)(p0 & 0x3FFFFu) * D + 2 * sub]);
    float2 x1 = __half22float2(
        *(const __half2*)&x[(size_t)(p1 & 0x3FFFFu) * D + 2 * sub]);
    float2 x2 = __half22float2(
        *(const __half2*)&x[(size_t)(p2 & 0x3FFFFu) * D + 2 * sub]);
    float2 x3 = __half22float2(
        *(const __half2*)&x[(size_t)(p3 & 0x3FFFFu) * D + 2 * sub]);
    float v0 = (float)(p0 >> 18), v1 = (float)(p1 >> 18);
    float v2 = (float)(p2 >> 18), v3 = (float)(p3 >> 18);
    ax += v0 * x0.x + v1 * x1.x + v2 * x2.x + v3 * x3.x;
    ay += v0 * x0.y + v1 * x1.y + v2 * x2.y + v3 * x3.y;
  }
  for (; e < e2; ++e) {
    unsigned p = __builtin_nontemporal_load(&ec[e]);
    float2 xv = __half22float2(
        *(const __half2*)&x[(size_t)(p & 0x3FFFFu) * D + 2 * sub]);
    float v = (float)(p >> 18);
    ax += v * xv.x;
    ay += v * xv.y;
  }
  float fw = filt[c];
  float f = (fw > 0.f ? fw : LEAKY * fw) * (1.f / VSCALE);
  *(__half2*)&y[(size_t)c * D + 2 * sub] = __floats2half2_rn(ax * f, ay * f);
}

// ---------------------------------------------------------------------------
// pass 2 (CSR by row): x[r] = sum val*y[src]
// ---------------------------------------------------------------------------
__global__ __launch_bounds__(256) void spmm_row_kernel(
    const int* __restrict__ ptrr, const unsigned* __restrict__ er,
    const __half* __restrict__ y, __half* __restrict__ x) {
  int w = blockIdx.x * 4 + (threadIdx.x >> 6);
  int r = w * 2 + ((threadIdx.x >> 5) & 1);
  if (r >= N_UB) return;
  int sub = threadIdx.x & 31;
  int e = ptrr[r], e2 = ptrr[r + 1];
  float ax = 0.f, ay = 0.f;
  for (; e + 4 <= e2; e += 4) {
    unsigned p0 = __builtin_nontemporal_load(&er[e]);
    unsigned p1 = __builtin_nontemporal_load(&er[e + 1]);
    unsigned p2 = __builtin_nontemporal_load(&er[e + 2]);
    unsigned p3 = __builtin_nontemporal_load(&er[e + 3]);
    float2 y0 = __half22float2(
        *(const __half2*)&y[(size_t)(p0 & 0x3FFFFu) * D + 2 * sub]);
    float2 y1 = __half22float2(
        *(const __half2*)&y[(size_t)(p1 & 0x3FFFFu) * D + 2 * sub]);
    float2 y2 = __half22float2(
        *(const __half2*)&y[(size_t)(p2 & 0x3FFFFu) * D + 2 * sub]);
    float2 y3 = __half22float2(
        *(const __half2*)&y[(size_t)(p3 & 0x3FFFFu) * D + 2 * sub]);
    float v0 = (float)(p0 >> 18), v1 = (float)(p1 >> 18);
    float v2 = (float)(p2 >> 18), v3 = (float)(p3 >> 18);
    ax += v0 * y0.x + v1 * y1.x + v2 * y2.x + v3 * y3.x;
    ay += v0 * y0.y + v1 * y1.y + v2 * y2.y + v3 * y3.y;
  }
  for (; e < e2; ++e) {
    unsigned p = __builtin_nontemporal_load(&er[e]);
    float2 yv = __half22float2(
        *(const __half2*)&y[(size_t)(p & 0x3FFFFu) * D + 2 * sub]);
    float v = (float)(p >> 18);
    ax += v * yv.x;
    ay += v * yv.y;
  }
  *(__half2*)&x[(size_t)r * D + 2 * sub] =
      __floats2half2_rn(ax * (1.f / VSCALE), ay * (1.f / VSCALE));
}

// ---------------------------------------------------------------------------
// last layer pass 2 ONLY at gathered rows, accumulated into uacc/bacc (fp32)
// ---------------------------------------------------------------------------
__global__ __launch_bounds__(256) void spmm_gather_last_kernel(
    const int* __restrict__ ptrr, const unsigned* __restrict__ er,
    const __half* __restrict__ y, const int* __restrict__ u_idx,
    const int* __restrict__ b_idx, float* __restrict__ uacc,
    float* __restrict__ bacc) {
  int w = blockIdx.x * 4 + (threadIdx.x >> 6);
  int i = w * 2 + ((threadIdx.x >> 5) & 1);
  if (i >= 3 * BATCH) return;
  int sub = threadIdx.x & 31;
  int row;
  float* dst;
  if (i < BATCH) {
    row = u_idx[i];
    dst = &uacc[(size_t)i * D];
  } else {
    int j = i - BATCH;
    row = NU + b_idx[j];
    dst = &bacc[(size_t)j * D];
  }
  int e = ptrr[row], e2 = ptrr[row + 1];
  float ax = 0.f, ay = 0.f;
  for (; e + 2 <= e2; e += 2) {
    unsigned p0 = er[e], p1 = er[e + 1];
    float2 y0 = __half22float2(
        *(const __half2*)&y[(size_t)(p0 & 0x3FFFFu) * D + 2 * sub]);
    float2 y1 = __half22float2(
        *(const __half2*)&y[(size_t)(p1 & 0x3FFFFu) * D + 2 * sub]);
    float v0 = (float)(p0 >> 18), v1 = (float)(p1 >> 18);
    ax += v0 * y0.x + v1 * y1.x;
    ay += v0 * y0.y + v1 * y1.y;
  }
  if (e < e2) {
    unsigned p = er[e];
    float2 yv = __half22float2(
        *(const __half2*)&y[(size_t)(p & 0x3FFFFu) * D + 2 * sub]);
    float v = (float)(p >> 18);
    ax += v * yv.x;
    ay += v * yv.y;
  }
  float2* dp = (float2*)&dst[2 * sub];
  float2 d = *dp;
  d.x += ax * (1.f / VSCALE);
  d.y += ay * (1.f / VSCALE);
  *dp = d;
}

// ---------------------------------------------------------------------------
// gather-accumulate (x0 + intermediate layers)
// ---------------------------------------------------------------------------
__global__ __launch_bounds__(256) void gather_acc_kernel(
    const __half* __restrict__ x, const int* __restrict__ u_idx,
    const int* __restrict__ b_idx, float* __restrict__ uacc,
    float* __restrict__ bacc) {
  int w = blockIdx.x * 4 + (threadIdx.x >> 6);
  int i = w * 2 + ((threadIdx.x >> 5) & 1);
  if (i >= 3 * BATCH) return;
  int sub = threadIdx.x & 31;
  int src;
  float* dst;
  if (i < BATCH) {
    src = u_idx[i];
    dst = &uacc[(size_t)i * D];
  } else {
    int j = i - BATCH;
    src = NU + b_idx[j];
    dst = &bacc[(size_t)j * D];
  }
  float2 xf =
      __half22float2(*(const __half2*)&x[(size_t)src * D + 2 * sub]);
  float2* dp = (float2*)&dst[2 * sub];
  float2 d = *dp;
  d.x += xf.x;
  d.y += xf.y;
  *dp = d;
}

// ---------------------------------------------------------------------------
// loss
// ---------------------------------------------------------------------------
__global__ __launch_bounds__(256) void loss_kernel(
    const float* __restrict__ uacc, const float* __restrict__ bacc,
    float* __restrict__ out) {
  int w = blockIdx.x * 4 + (threadIdx.x >> 6);
  int i = w * 2 + ((threadIdx.x >> 5) & 1);
  if (i >= BATCH) return;
  int sub = threadIdx.x & 31;
  float2 u = *(const float2*)&uacc[(size_t)i * D + 2 * sub];
  float2 b0 = *(const float2*)&bacc[(size_t)(2 * i) * D + 2 * sub];
  float2 b1 = *(const float2*)&bacc[(size_t)(2 * i + 1) * D + 2 * sub];
  float t = (u.x * (b1.x - b0.x) + u.y * (b1.y - b0.y)) * (1.f / 16.f);
  for (int off = 16; off; off >>= 1) t += __shfl_down(t, off, 32);
  if (sub == 0) {
    float z = t;
    float sp = z > 0.f ? z + log1pf(expf(-z)) : log1pf(expf(z));
    atomicAdd(&out[0], sp * (1.f / (float)BATCH));
  }
}

extern "C" void kernel_launch(void* const* d_in, const int* in_sizes, int n_in,
                              void* d_out, int out_size, void* d_ws,
                              size_t ws_size, hipStream_t stream) {
  const float* emb_u = (const float*)d_in[0];
  const float* emb_b = (const float*)d_in[1];
  const float* filter_w = (const float*)d_in[2];
  const float* vals = (const float*)d_in[3];
  const int* rows = (const int*)d_in[4];
  const int* cols = (const int*)d_in[5];
  const int* u_idx = (const int*)d_in[6];
  const int* b_idx = (const int*)d_in[7];
  float* out = (float*)d_out;

  // workspace layout: bucket buffers (dead after CSR build) are ALIASED with
  // yH + uacc + bacc (live only after CSR build).
  char* base = (char*)d_ws;
  u64* bufC = (u64*)base;                              // NWC*CAPC u64
  u64* bufR = bufC + (size_t)NWC * CAPC;               // NWR*CAPR u64
  __half* yH = (__half*)base;                          // N_IU*D halves (alias)
  float* uacc = (float*)(base + (size_t)N_IU * D * 2); // BATCH*D (alias)
  float* bacc = uacc + (size_t)BATCH * D;              // 2*BATCH*D (alias)
  char* after = base + ((size_t)NWC * CAPC + (size_t)NWR * CAPR) * 8;
  __half* xA = (__half*)after;                         // N_UB*D halves
  unsigned* ec = (unsigned*)(xA + (size_t)N_UB * D);   // NNZ
  unsigned* er = ec + NNZ;                             // NNZ
  int* ptrc = (int*)(er + NNZ);                        // N_IU+1
  int* ptrr = ptrc + (N_IU + 1);                       // N_UB+1
  int* gcurC = ptrr + (N_UB + 1);                      // NWC
  int* gcurR = gcurC + NWC;                            // NWR

  hipMemsetAsync(out, 0, 2 * sizeof(float), stream);
  hipMemsetAsync(gcurC, 0, NWIN * sizeof(int), stream);

  // bucket edges by node-window (both sides)
  bucket_kernel<<<NBLK_B, 1024, 0, stream>>>(rows, cols, vals, gcurC, gcurR,
                                             bufC, bufR);
  // per-window LDS counting sort (-> ptr + ec/er), fused with concat+l2
  csr_concat_kernel<<<NWIN + CONCAT_BLKS, 1024, 0, stream>>>(
      bufC, bufR, gcurC, gcurR, ec, er, ptrc, ptrr, emb_u, emb_b, xA, out);
  // bucket buffers are now dead -> zero the aliased uacc/bacc region
  hipMemsetAsync(uacc, 0, (size_t)3 * BATCH * D * sizeof(float), stream);
  // x0 contribution to gathered rows
  gather_acc_kernel<<<(3 * BATCH + 7) / 8, 256, 0, stream>>>(xA, u_idx, b_idx,
                                                             uacc, bacc);

  // ---- 3 layers ----
  for (int l = 0; l < NLAYER; ++l) {
    spmm_col_kernel<<<(N_IU + 7) / 8, 256, 0, stream>>>(
        ptrc, ec, xA, filter_w + (size_t)l * N_IU, yH);
    if (l < NLAYER - 1) {
      spmm_row_kernel<<<(N_UB + 7) / 8, 256, 0, stream>>>(ptrr, er, yH, xA);
      gather_acc_kernel<<<(3 * BATCH + 7) / 8, 256, 0, stream>>>(
          xA, u_idx, b_idx, uacc, bacc);
    } else {
      spmm_gather_last_kernel<<<(3 * BATCH + 7) / 8, 256, 0, stream>>>(
          ptrr, er, yH, u_idx, b_idx, uacc, bacc);
    }
  }

  loss_kernel<<<(BATCH + 7) / 8, 256, 0, stream>>>(uacc, bacc, out);
}

// Round 7
// 415.355 us; speedup vs baseline: 1.9055x; 1.3059x over previous
//
#include <hip/hip_runtime.h>
#include <math.h>

#define NU 100000
#define NB 50000
#define NI 100000
#define D 64
#define NLAYER 3
#define NNZ 2000000
#define BATCH 8192
#define LEAKY 0.2f
#define N_UB (NU + NB)   // 150000
#define N_IU (NI + NU)   // 200000

#define VSCALE 16383.f   // 14-bit fixed-point for vals in [0,1)

// ---- windowed CSR build params ----
#define WBITS 11
#define WSZ 2048                        // node window (small -> many blocks)
#define NWC ((N_IU + WSZ - 1) / WSZ)    // 98
#define NWR ((N_UB + WSZ - 1) / WSZ)    // 74
#define NWIN (NWC + NWR)                // 172
#define CAPC 21504                      // mean 20480 + 7.2 sigma
#define CAPR 28672                      // mean 27307 + 8.3 sigma
#define EPB 8192                        // edges per bucket block
#define NBLK_B ((NNZ + EPB - 1) / EPB)  // 245
#define CONCAT_BLKS 512

typedef unsigned long long u64;
typedef float v2f __attribute__((ext_vector_type(2)));

// ---- fp8 e4m3 x4 pack/unpack (hardware cvt; roundtrip-consistent) ----
__device__ __forceinline__ unsigned pack_fp8x4(float a, float b, float c,
                                               float d) {
  int lo = __builtin_amdgcn_cvt_pk_fp8_f32(a, b, 0, false);
  int pk = __builtin_amdgcn_cvt_pk_fp8_f32(c, d, lo, true);
  return (unsigned)pk;
}
__device__ __forceinline__ void unpack_fp8x4(unsigned w, float f[4]) {
  v2f lo = __builtin_amdgcn_cvt_pk_f32_fp8((int)w, false);
  v2f hi = __builtin_amdgcn_cvt_pk_f32_fp8((int)w, true);
  f[0] = lo[0];
  f[1] = lo[1];
  f[2] = hi[0];
  f[3] = hi[1];
}

// ---------------------------------------------------------------------------
// bucket pass: partition edges into 2048-node windows for both sides.
// record: payload32 = q<<18 | partner ; rec = payload<<11 | node_local
// ---------------------------------------------------------------------------
__global__ __launch_bounds__(1024) void bucket_kernel(
    const int* __restrict__ rows, const int* __restrict__ cols,
    const float* __restrict__ vals, int* __restrict__ gcurC,
    int* __restrict__ gcurR, u64* __restrict__ bufC, u64* __restrict__ bufR) {
  __shared__ int cntw[NWIN];
  __shared__ int basew[NWIN];
  int t = threadIdx.x;
  if (t < NWIN) cntw[t] = 0;
  __syncthreads();
  int e0 = blockIdx.x * EPB;
  int e1 = e0 + EPB;
  if (e1 > NNZ) e1 = NNZ;
  for (int e = e0 + t; e < e1; e += 1024) {
    int c = cols[e];
    int r = rows[e];
    atomicAdd(&cntw[c >> WBITS], 1);
    atomicAdd(&cntw[NWC + (r >> WBITS)], 1);
  }
  __syncthreads();
  if (t < NWC)
    basew[t] = atomicAdd(&gcurC[t], cntw[t]);
  else if (t < NWIN)
    basew[t] = atomicAdd(&gcurR[t - NWC], cntw[t]);
  __syncthreads();
  if (t < NWIN) cntw[t] = 0;  // reuse as local cursors
  __syncthreads();
  for (int e = e0 + t; e < e1; e += 1024) {
    int c = cols[e];
    int r = rows[e];
    unsigned q = __float2uint_rn(vals[e] * VSCALE);
    int wc = c >> WBITS;
    int wr = r >> WBITS;
    int oc = atomicAdd(&cntw[wc], 1);
    u64 recC = ((u64)((q << 18) | (unsigned)r) << WBITS) |
               (unsigned)(c & (WSZ - 1));
    bufC[(size_t)wc * CAPC + basew[wc] + oc] = recC;
    int orr = atomicAdd(&cntw[NWC + wr], 1);
    u64 recR = ((u64)((q << 18) | (unsigned)c) << WBITS) |
               (unsigned)(r & (WSZ - 1));
    bufR[(size_t)wr * CAPR + basew[NWC + wr] + orr] = recR;
  }
}

// ---------------------------------------------------------------------------
// fused dispatch:
//   blocks [0, NWIN): per-window LDS counting sort -> ptr slice + ec/er
//   blocks [NWIN, ...): concat emb -> x (fp8) + l2 reduction
// ---------------------------------------------------------------------------
__global__ __launch_bounds__(1024) void csr_concat_kernel(
    const u64* __restrict__ bufC, const u64* __restrict__ bufR,
    const int* __restrict__ gcurC, const int* __restrict__ gcurR,
    unsigned* __restrict__ ec, unsigned* __restrict__ er,
    int* __restrict__ ptrc, int* __restrict__ ptrr,
    const float* __restrict__ emb_u, const float* __restrict__ emb_b,
    unsigned* __restrict__ x, float* __restrict__ out) {
  __shared__ int lcnt[WSZ];
  __shared__ int part[1024];
  __shared__ float fsum[16];
  int blk = blockIdx.x;
  int t = threadIdx.x;

  if (blk >= NWIN) {
    // ---------------- concat + l2 path (fp8 out) ----------------
    const int total4 = (N_UB * D) / 4;
    const int nu4 = (NU * D) / 4;
    float sq = 0.f;
    for (int i = (blk - NWIN) * 1024 + t; i < total4; i += CONCAT_BLKS * 1024) {
      float4 v = (i < nu4) ? ((const float4*)emb_u)[i]
                           : ((const float4*)emb_b)[i - nu4];
      sq += v.x * v.x + v.y * v.y + v.z * v.z + v.w * v.w;
      x[i] = pack_fp8x4(v.x, v.y, v.z, v.w);
    }
    for (int off = 32; off; off >>= 1) sq += __shfl_down(sq, off);
    if ((t & 63) == 0) fsum[t >> 6] = sq;
    __syncthreads();
    if (t == 0) {
      float s = 0.f;
      for (int k = 0; k < 16; ++k) s += fsum[k];
      atomicAdd(&out[1], s * (0.5f / (float)NU));
    }
    return;
  }

  // ---------------- windowed counting-sort path ----------------
  bool cside = blk < NWC;
  int win = cside ? blk : blk - NWC;
  const u64* buf = cside ? bufC + (size_t)win * CAPC : bufR + (size_t)win * CAPR;
  const int* gsz = cside ? gcurC : gcurR;
  int nwin = cside ? NWC : NWR;
  int nnode = cside ? N_IU : N_UB;
  unsigned* eo = cside ? ec : er;
  int* ptr = cside ? ptrc : ptrr;
  int cnt = gsz[win];
  int winbase = 0;
  for (int w = 0; w < win; ++w) winbase += gsz[w];

  lcnt[t] = 0;
  lcnt[t + 1024] = 0;
  __syncthreads();
  for (int i = t; i < cnt; i += 1024)
    atomicAdd(&lcnt[(int)(buf[i] & (WSZ - 1))], 1);
  __syncthreads();
  int i0 = 2 * t;
  int a = lcnt[i0], b = lcnt[i0 + 1];
  int s = a + b;
  part[t] = s;
  __syncthreads();
  for (int off = 1; off < 1024; off <<= 1) {
    int v = (t >= off) ? part[t - off] : 0;
    __syncthreads();
    part[t] += v;
    __syncthreads();
  }
  int excl = part[t] - s;
  lcnt[i0] = excl;
  lcnt[i0 + 1] = excl + a;
  __syncthreads();
  int gnode0 = win * WSZ;
  for (int j = t; j < WSZ; j += 1024) {
    int g = gnode0 + j;
    if (g < nnode) ptr[g] = winbase + lcnt[j];
  }
  if (t == 0 && win == nwin - 1) ptr[nnode] = NNZ;
  __syncthreads();
  for (int i = t; i < cnt; i += 1024) {
    u64 rec = buf[i];
    int pos = winbase + atomicAdd(&lcnt[(int)(rec & (WSZ - 1))], 1);
    eo[pos] = (unsigned)(rec >> WBITS);
  }
}

// ---------------------------------------------------------------------------
// pass 1 (CSR by col): y[c] = leaky(filt[c]) * sum val*x[src]
// fp8 rows: 16 lanes/row, u32 (4 dims) per lane, 4 rows per wave; unroll 4.
// One 64B line per row gather.
// ---------------------------------------------------------------------------
__global__ __launch_bounds__(256) void spmm_col_kernel(
    const int* __restrict__ ptrc, const unsigned* __restrict__ ec,
    const unsigned* __restrict__ x, const float* __restrict__ filt,
    unsigned* __restrict__ y) {
  int wv = blockIdx.x * 4 + (threadIdx.x >> 6);
  int lane = threadIdx.x & 63;
  int g = lane & 15;
  int c = wv * 4 + (lane >> 4);
  if (c >= N_IU) return;
  int e = ptrc[c], e2 = ptrc[c + 1];
  float a0 = 0.f, a1 = 0.f, a2 = 0.f, a3 = 0.f;
  for (; e + 4 <= e2; e += 4) {
    unsigned p0 = __builtin_nontemporal_load(&ec[e]);
    unsigned p1 = __builtin_nontemporal_load(&ec[e + 1]);
    unsigned p2 = __builtin_nontemporal_load(&ec[e + 2]);
    unsigned p3 = __builtin_nontemporal_load(&ec[e + 3]);
    unsigned w0 = x[(size_t)(p0 & 0x3FFFFu) * 16 + g];
    unsigned w1 = x[(size_t)(p1 & 0x3FFFFu) * 16 + g];
    unsigned w2 = x[(size_t)(p2 & 0x3FFFFu) * 16 + g];
    unsigned w3 = x[(size_t)(p3 & 0x3FFFFu) * 16 + g];
    float f0[4], f1[4], f2[4], f3[4];
    unpack_fp8x4(w0, f0);
    unpack_fp8x4(w1, f1);
    unpack_fp8x4(w2, f2);
    unpack_fp8x4(w3, f3);
    float v0 = (float)(p0 >> 18), v1 = (float)(p1 >> 18);
    float v2 = (float)(p2 >> 18), v3 = (float)(p3 >> 18);
    a0 += v0 * f0[0] + v1 * f1[0] + v2 * f2[0] + v3 * f3[0];
    a1 += v0 * f0[1] + v1 * f1[1] + v2 * f2[1] + v3 * f3[1];
    a2 += v0 * f0[2] + v1 * f1[2] + v2 * f2[2] + v3 * f3[2];
    a3 += v0 * f0[3] + v1 * f1[3] + v2 * f2[3] + v3 * f3[3];
  }
  for (; e < e2; ++e) {
    unsigned p = __builtin_nontemporal_load(&ec[e]);
    unsigned w = x[(size_t)(p & 0x3FFFFu) * 16 + g];
    float f4[4];
    unpack_fp8x4(w, f4);
    float v = (float)(p >> 18);
    a0 += v * f4[0];
    a1 += v * f4[1];
    a2 += v * f4[2];
    a3 += v * f4[3];
  }
  float fw = filt[c];
  float f = (fw > 0.f ? fw : LEAKY * fw) * (1.f / VSCALE);
  y[(size_t)c * 16 + g] = pack_fp8x4(a0 * f, a1 * f, a2 * f, a3 * f);
}

// ---------------------------------------------------------------------------
// pass 2 (CSR by row): x[r] = sum val*y[src]
// ---------------------------------------------------------------------------
__global__ __launch_bounds__(256) void spmm_row_kernel(
    const int* __restrict__ ptrr, const unsigned* __restrict__ er,
    const unsigned* __restrict__ y, unsigned* __restrict__ x) {
  int wv = blockIdx.x * 4 + (threadIdx.x >> 6);
  int lane = threadIdx.x & 63;
  int g = lane & 15;
  int r = wv * 4 + (lane >> 4);
  if (r >= N_UB) return;
  int e = ptrr[r], e2 = ptrr[r + 1];
  float a0 = 0.f, a1 = 0.f, a2 = 0.f, a3 = 0.f;
  for (; e + 4 <= e2; e += 4) {
    unsigned p0 = __builtin_nontemporal_load(&er[e]);
    unsigned p1 = __builtin_nontemporal_load(&er[e + 1]);
    unsigned p2 = __builtin_nontemporal_load(&er[e + 2]);
    unsigned p3 = __builtin_nontemporal_load(&er[e + 3]);
    unsigned w0 = y[(size_t)(p0 & 0x3FFFFu) * 16 + g];
    unsigned w1 = y[(size_t)(p1 & 0x3FFFFu) * 16 + g];
    unsigned w2 = y[(size_t)(p2 & 0x3FFFFu) * 16 + g];
    unsigned w3 = y[(size_t)(p3 & 0x3FFFFu) * 16 + g];
    float f0[4], f1[4], f2[4], f3[4];
    unpack_fp8x4(w0, f0);
    unpack_fp8x4(w1, f1);
    unpack_fp8x4(w2, f2);
    unpack_fp8x4(w3, f3);
    float v0 = (float)(p0 >> 18), v1 = (float)(p1 >> 18);
    float v2 = (float)(p2 >> 18), v3 = (float)(p3 >> 18);
    a0 += v0 * f0[0] + v1 * f1[0] + v2 * f2[0] + v3 * f3[0];
    a1 += v0 * f0[1] + v1 * f1[1] + v2 * f2[1] + v3 * f3[1];
    a2 += v0 * f0[2] + v1 * f1[2] + v2 * f2[2] + v3 * f3[2];
    a3 += v0 * f0[3] + v1 * f1[3] + v2 * f2[3] + v3 * f3[3];
  }
  for (; e < e2; ++e) {
    unsigned p = __builtin_nontemporal_load(&er[e]);
    unsigned w = y[(size_t)(p & 0x3FFFFu) * 16 + g];
    float f4[4];
    unpack_fp8x4(w, f4);
    float v = (float)(p >> 18);
    a0 += v * f4[0];
    a1 += v * f4[1];
    a2 += v * f4[2];
    a3 += v * f4[3];
  }
  const float s = 1.f / VSCALE;
  x[(size_t)r * 16 + g] = pack_fp8x4(a0 * s, a1 * s, a2 * s, a3 * s);
}

// ---------------------------------------------------------------------------
// last layer pass 2 ONLY at gathered rows, accumulated into uacc/bacc (fp32)
// ---------------------------------------------------------------------------
__global__ __launch_bounds__(256) void spmm_gather_last_kernel(
    const int* __restrict__ ptrr, const unsigned* __restrict__ er,
    const unsigned* __restrict__ y, const int* __restrict__ u_idx,
    const int* __restrict__ b_idx, float* __restrict__ uacc,
    float* __restrict__ bacc) {
  int wv = blockIdx.x * 4 + (threadIdx.x >> 6);
  int lane = threadIdx.x & 63;
  int g = lane & 15;
  int i = wv * 4 + (lane >> 4);
  if (i >= 3 * BATCH) return;
  int row;
  float* dst;
  if (i < BATCH) {
    row = u_idx[i];
    dst = &uacc[(size_t)i * D];
  } else {
    int j = i - BATCH;
    row = NU + b_idx[j];
    dst = &bacc[(size_t)j * D];
  }
  int e = ptrr[row], e2 = ptrr[row + 1];
  float a0 = 0.f, a1 = 0.f, a2 = 0.f, a3 = 0.f;
  for (; e < e2; ++e) {
    unsigned p = er[e];
    unsigned w = y[(size_t)(p & 0x3FFFFu) * 16 + g];
    float f4[4];
    unpack_fp8x4(w, f4);
    float v = (float)(p >> 18);
    a0 += v * f4[0];
    a1 += v * f4[1];
    a2 += v * f4[2];
    a3 += v * f4[3];
  }
  const float s = 1.f / VSCALE;
  float4* dp = (float4*)&dst[4 * g];
  float4 d = *dp;
  d.x += a0 * s;
  d.y += a1 * s;
  d.z += a2 * s;
  d.w += a3 * s;
  *dp = d;
}

// ---------------------------------------------------------------------------
// gather-accumulate (x0 + intermediate layers): fp8 x -> fp32 acc
// ---------------------------------------------------------------------------
__global__ __launch_bounds__(256) void gather_acc_kernel(
    const unsigned* __restrict__ x, const int* __restrict__ u_idx,
    const int* __restrict__ b_idx, float* __restrict__ uacc,
    float* __restrict__ bacc) {
  int wv = blockIdx.x * 4 + (threadIdx.x >> 6);
  int lane = threadIdx.x & 63;
  int g = lane & 15;
  int i = wv * 4 + (lane >> 4);
  if (i >= 3 * BATCH) return;
  int src;
  float* dst;
  if (i < BATCH) {
    src = u_idx[i];
    dst = &uacc[(size_t)i * D];
  } else {
    int j = i - BATCH;
    src = NU + b_idx[j];
    dst = &bacc[(size_t)j * D];
  }
  float f4[4];
  unpack_fp8x4(x[(size_t)src * 16 + g], f4);
  float4* dp = (float4*)&dst[4 * g];
  float4 d = *dp;
  d.x += f4[0];
  d.y += f4[1];
  d.z += f4[2];
  d.w += f4[3];
  *dp = d;
}

// ---------------------------------------------------------------------------
// loss: z = dot(u, b1-b0)/16; loss = mean softplus(z). half-wave per elem.
// ---------------------------------------------------------------------------
__global__ __launch_bounds__(256) void loss_kernel(
    const float* __restrict__ uacc, const float* __restrict__ bacc,
    float* __restrict__ out) {
  int w = blockIdx.x * 4 + (threadIdx.x >> 6);
  int i = w * 2 + ((threadIdx.x >> 5) & 1);
  if (i >= BATCH) return;
  int sub = threadIdx.x & 31;
  float2 u = *(const float2*)&uacc[(size_t)i * D + 2 * sub];
  float2 b0 = *(const float2*)&bacc[(size_t)(2 * i) * D + 2 * sub];
  float2 b1 = *(const float2*)&bacc[(size_t)(2 * i + 1) * D + 2 * sub];
  float t = (u.x * (b1.x - b0.x) + u.y * (b1.y - b0.y)) * (1.f / 16.f);
  for (int off = 16; off; off >>= 1) t += __shfl_down(t, off, 32);
  if (sub == 0) {
    float z = t;
    float sp = z > 0.f ? z + log1pf(expf(-z)) : log1pf(expf(z));
    atomicAdd(&out[0], sp * (1.f / (float)BATCH));
  }
}

extern "C" void kernel_launch(void* const* d_in, const int* in_sizes, int n_in,
                              void* d_out, int out_size, void* d_ws,
                              size_t ws_size, hipStream_t stream) {
  const float* emb_u = (const float*)d_in[0];
  const float* emb_b = (const float*)d_in[1];
  const float* filter_w = (const float*)d_in[2];
  const float* vals = (const float*)d_in[3];
  const int* rows = (const int*)d_in[4];
  const int* cols = (const int*)d_in[5];
  const int* u_idx = (const int*)d_in[6];
  const int* b_idx = (const int*)d_in[7];
  float* out = (float*)d_out;

  // workspace layout: bucket buffers (dead after CSR build) ALIASED with
  // yH + uacc + bacc (live only after CSR build).
  char* base = (char*)d_ws;
  u64* bufC = (u64*)base;                               // NWC*CAPC u64
  u64* bufR = bufC + (size_t)NWC * CAPC;                // NWR*CAPR u64
  unsigned* yH = (unsigned*)base;                       // N_IU*16 u32 (alias)
  float* uacc = (float*)(base + (size_t)N_IU * D);      // BATCH*D (alias)
  float* bacc = uacc + (size_t)BATCH * D;               // 2*BATCH*D (alias)
  char* after = base + ((size_t)NWC * CAPC + (size_t)NWR * CAPR) * 8;
  unsigned* xA = (unsigned*)after;                      // N_UB*16 u32
  unsigned* ec = xA + (size_t)N_UB * 16;                // NNZ
  unsigned* er = ec + NNZ;                              // NNZ
  int* ptrc = (int*)(er + NNZ);                         // N_IU+1
  int* ptrr = ptrc + (N_IU + 1);                        // N_UB+1
  int* gcurC = ptrr + (N_UB + 1);                       // NWC
  int* gcurR = gcurC + NWC;                             // NWR

  hipMemsetAsync(out, 0, 2 * sizeof(float), stream);
  hipMemsetAsync(gcurC, 0, NWIN * sizeof(int), stream);

  // bucket edges by node-window (both sides)
  bucket_kernel<<<NBLK_B, 1024, 0, stream>>>(rows, cols, vals, gcurC, gcurR,
                                             bufC, bufR);
  // per-window LDS counting sort (-> ptr + ec/er), fused with concat+l2
  csr_concat_kernel<<<NWIN + CONCAT_BLKS, 1024, 0, stream>>>(
      bufC, bufR, gcurC, gcurR, ec, er, ptrc, ptrr, emb_u, emb_b, xA, out);
  // bucket buffers now dead -> zero the aliased uacc/bacc region
  hipMemsetAsync(uacc, 0, (size_t)3 * BATCH * D * sizeof(float), stream);
  // x0 contribution to gathered rows
  gather_acc_kernel<<<(3 * BATCH + 15) / 16, 256, 0, stream>>>(
      xA, u_idx, b_idx, uacc, bacc);

  // ---- 3 layers ----
  for (int l = 0; l < NLAYER; ++l) {
    spmm_col_kernel<<<(N_IU + 15) / 16, 256, 0, stream>>>(
        ptrc, ec, xA, filter_w + (size_t)l * N_IU, yH);
    if (l < NLAYER - 1) {
      spmm_row_kernel<<<(N_UB + 15) / 16, 256, 0, stream>>>(ptrr, er, yH, xA);
      gather_acc_kernel<<<(3 * BATCH + 15) / 16, 256, 0, stream>>>(
          xA, u_idx, b_idx, uacc, bacc);
    } else {
      spmm_gather_last_kernel<<<(3 * BATCH + 15) / 16, 256, 0, stream>>>(
          ptrr, er, yH, u_idx, b_idx, uacc, bacc);
    }
  }

  loss_kernel<<<(BATCH + 7) / 8, 256, 0, stream>>>(uacc, bacc, out);
}